// Round 1
// baseline (518.037 us; speedup 1.0000x reference)
//
#include <hip/hip_runtime.h>
#include <hip/hip_bf16.h>

#define B_    1024
#define N_    64
#define F_    1024
#define H1_   256
#define H2_   128
#define NC_   128
#define ALPHA 0.2f
#define BN_EPS 1e-5f

typedef __attribute__((ext_vector_type(4))) float  f32x4;
typedef __attribute__((ext_vector_type(8))) __bf16 bf16x8;
typedef __attribute__((ext_vector_type(4))) __bf16 bf16x4;

__device__ inline float sign_ref(float v) {
    // matches v / max(|v|, 1e-12): exact +-1 for |v| >= 1e-12
    float s = copysignf(1.0f, v);
    return (fabsf(v) >= 1e-12f) ? s : v * 1e12f;
}

__device__ inline float blk_reduce(float v, float* buf) {
    #pragma unroll
    for (int o = 32; o > 0; o >>= 1) v += __shfl_xor(v, o, 64);
    __syncthreads();               // protect buf reuse across calls
    const int wave = threadIdx.x >> 6, lane = threadIdx.x & 63;
    if (lane == 0) buf[wave] = v;
    __syncthreads();
    float r = 0.f;
    if (threadIdx.x == 0) {
        const int nw = blockDim.x >> 6;
        for (int i = 0; i < nw; ++i) r += buf[i];
    }
    return r;  // valid on thread 0 only
}

// ---------------------------------------------------------------------------
// Prep: W1,W2 -> bf16; w1a = W1^T a11; w2a = W2^T a21; c1 = b1.a11; c2 = b2.a21
// grid: 294 blocks x 256
// ---------------------------------------------------------------------------
__global__ __launch_bounds__(256) void k_prep(
    const float* __restrict__ W1, const float* __restrict__ W2,
    const float* __restrict__ b1, const float* __restrict__ a11,
    const float* __restrict__ b2, const float* __restrict__ a21,
    __bf16* __restrict__ W1b, __bf16* __restrict__ W2b,
    float* __restrict__ w1a, float* __restrict__ w2a, float* __restrict__ cscal)
{
    __shared__ float rbuf[8];
    const int blk = blockIdx.x, tid = threadIdx.x;
    if (blk < 256) {                       // W1 convert: 262144 elems
        const int i0 = blk * 1024 + tid * 4;
        float4 v = *(const float4*)(W1 + i0);
        bf16x4 p = { (__bf16)v.x, (__bf16)v.y, (__bf16)v.z, (__bf16)v.w };
        *(bf16x4*)(W1b + i0) = p;
    } else if (blk < 288) {                // W2 convert: 32768 elems
        const int i0 = (blk - 256) * 1024 + tid * 4;
        float4 v = *(const float4*)(W2 + i0);
        bf16x4 p = { (__bf16)v.x, (__bf16)v.y, (__bf16)v.z, (__bf16)v.w };
        *(bf16x4*)(W2b + i0) = p;
    } else if (blk < 292) {                // w1a[f] = sum_h W1[h,f] a11[h]
        const int f = (blk - 288) * 256 + tid;
        float s = 0.f;
        for (int h = 0; h < H1_; ++h) s += W1[h * F_ + f] * a11[h];
        w1a[f] = s;
    } else if (blk == 292) {               // w2a[k] = sum_h W2[h,k] a21[h]
        float s = 0.f;
        for (int h = 0; h < H2_; ++h) s += W2[h * H1_ + tid] * a21[h];
        w2a[tid] = s;
    } else {                               // c1, c2
        float v1 = b1[tid] * a11[tid];
        float v2 = (tid < H2_) ? b2[tid] * a21[tid] : 0.f;
        float r1 = blk_reduce(v1, rbuf);
        float r2 = blk_reduce(v2, rbuf);
        if (tid == 0) { cscal[0] = r1; cscal[1] = r2; }
    }
}

// ---------------------------------------------------------------------------
// sself1[b] = sum_f sign(x[b,f]) * w1a[f] + c1     grid: 1024 x 256
// ---------------------------------------------------------------------------
__global__ __launch_bounds__(256) void k_sself1(
    const float* __restrict__ x, const float* __restrict__ w1a,
    const float* __restrict__ cscal, float* __restrict__ sself1)
{
    __shared__ float rbuf[8];
    const int b = blockIdx.x, tid = threadIdx.x;
    const float* xb = x + (size_t)b * F_;
    float p = 0.f;
    for (int i = tid; i < F_; i += 256) p += sign_ref(xb[i]) * w1a[i];
    float r = blk_reduce(p, rbuf);
    if (tid == 0) sself1[b] = r + cscal[0];
}

// ---------------------------------------------------------------------------
// GEMM: C[M,BN] = T(A[M,K]) @ Bw[BN,K]^T + bias
//   MODE 0: T = sign (l2norm over singleton axis)
//   MODE 1: T = relu(alpha[row>>rshift]*a + beta[row>>rshift])   (BN+ReLU)
// tile 128 x BN, BK=64, bf16 MFMA 16x16x32, 256 threads (4 waves, 2x2)
// ---------------------------------------------------------------------------
template<int BN, int MODE>
__global__ __launch_bounds__(256, 1) void k_gemm(
    const float* __restrict__ A, const int K,
    const __bf16* __restrict__ Bw, const float* __restrict__ bias,
    const float* __restrict__ alpha, const float* __restrict__ beta,
    const int rshift, float* __restrict__ C)
{
    constexpr int BM = 128, BK = 64;
    constexpr int WN = BN / 2;
    constexpr int NF = WN / 16;  // 8 (BN=256) or 4 (BN=128)
    constexpr int MF = 4;
    constexpr int LDA = BK + 8;  // pad 16B to spread banks
    __shared__ __bf16 As[BM][LDA];
    __shared__ __bf16 Bs[BN][LDA];

    const int tid = threadIdx.x;
    const int wave = tid >> 6, lane = tid & 63;
    const int wm = wave & 1, wn = wave >> 1;
    const int rowin = lane & 15, kq = lane >> 4;
    const size_t m0 = (size_t)blockIdx.x * BM;

    f32x4 acc[MF][NF] = {};

    for (int k0 = 0; k0 < K; k0 += BK) {
        // ---- stage A (fp32 -> transform -> bf16) ----
        {
            const int cq = tid & 15;           // 16 quads of 4 floats = 64 cols
            const int r0 = tid >> 4;
            const float* Ap = A + m0 * K + k0 + cq * 4;
            #pragma unroll
            for (int rr = 0; rr < BM / 16; ++rr) {
                const int r = r0 + rr * 16;
                float4 v = *(const float4*)(Ap + (size_t)r * K);
                float4 t;
                if (MODE == 0) {
                    t.x = sign_ref(v.x); t.y = sign_ref(v.y);
                    t.z = sign_ref(v.z); t.w = sign_ref(v.w);
                } else {
                    const int g = (int)((m0 + r) >> rshift);
                    const float al = alpha[g], bb = beta[g];
                    t.x = fmaxf(fmaf(al, v.x, bb), 0.f);
                    t.y = fmaxf(fmaf(al, v.y, bb), 0.f);
                    t.z = fmaxf(fmaf(al, v.z, bb), 0.f);
                    t.w = fmaxf(fmaf(al, v.w, bb), 0.f);
                }
                bf16x4 p = { (__bf16)t.x, (__bf16)t.y, (__bf16)t.z, (__bf16)t.w };
                *(bf16x4*)&As[r][cq * 4] = p;
            }
        }
        // ---- stage B (bf16 copy) ----
        {
            const int cq = tid & 7;            // 8 quads of 8 bf16 = 64 cols
            const int r0 = tid >> 3;
            const __bf16* Bp = Bw + k0 + cq * 8;
            #pragma unroll
            for (int rr = 0; rr < BN / 32; ++rr) {
                const int r = r0 + rr * 32;
                *(bf16x8*)&Bs[r][cq * 8] = *(const bf16x8*)(Bp + (size_t)r * K);
            }
        }
        __syncthreads();
        #pragma unroll
        for (int ks = 0; ks < 2; ++ks) {
            bf16x8 af[MF], bv[NF];
            #pragma unroll
            for (int mi = 0; mi < MF; ++mi)
                af[mi] = *(const bf16x8*)&As[wm * 64 + mi * 16 + rowin][ks * 32 + kq * 8];
            #pragma unroll
            for (int ni = 0; ni < NF; ++ni)
                bv[ni] = *(const bf16x8*)&Bs[wn * WN + ni * 16 + rowin][ks * 32 + kq * 8];
            #pragma unroll
            for (int mi = 0; mi < MF; ++mi)
                #pragma unroll
                for (int ni = 0; ni < NF; ++ni)
                    acc[mi][ni] = __builtin_amdgcn_mfma_f32_16x16x32_bf16(
                        af[mi], bv[ni], acc[mi][ni], 0, 0, 0);
        }
        __syncthreads();
    }
    // ---- epilogue: C[row, col] = acc + bias[col] ----
    const int cr0 = (lane >> 4) * 4, cc = lane & 15;
    #pragma unroll
    for (int ni = 0; ni < NF; ++ni) {
        const int col = wn * WN + ni * 16 + cc;
        const float bs = bias[col];
        #pragma unroll
        for (int mi = 0; mi < MF; ++mi) {
            #pragma unroll
            for (int i = 0; i < 4; ++i) {
                const size_t row = m0 + wm * 64 + mi * 16 + cr0 + i;
                C[row * BN + col] = acc[mi][ni][i] + bs;
            }
        }
    }
}

// ---------------------------------------------------------------------------
// Layer-1 softmax + aggregation + per-b BN stats.  grid: 1024 x 256
// ---------------------------------------------------------------------------
__global__ __launch_bounds__(256) void k_agg1(
    const float* __restrict__ nbh1, const float* __restrict__ sself1,
    const float* __restrict__ a12, const float* __restrict__ g1p,
    const float* __restrict__ be1p, float* __restrict__ out1,
    float* __restrict__ alpha1, float* __restrict__ beta1)
{
    __shared__ float tile[N_ * H1_];   // 64 KiB
    __shared__ float a12s[H1_];
    __shared__ float sv[N_];
    __shared__ float rbuf[8];
    const int b = blockIdx.x, tid = threadIdx.x;
    const float* src = nbh1 + (size_t)b * N_ * H1_;
    for (int i = tid; i < N_ * H1_ / 4; i += 256)
        ((float4*)tile)[i] = ((const float4*)src)[i];
    a12s[tid] = a12[tid];
    __syncthreads();
    // scores: s[n] = sself + nbh1[b,n,:].a12, leaky
    {
        const int n = tid >> 2, q = tid & 3;
        float p = 0.f;
        #pragma unroll 4
        for (int i = 0; i < 64; ++i) {
            const int h = q * 64 + ((i + tid) & 63);  // stagger banks
            p += tile[n * H1_ + h] * a12s[h];
        }
        p += __shfl_xor(p, 1); p += __shfl_xor(p, 2);
        if (q == 0) {
            float s = sself1[b] + p;
            sv[n] = s > 0.f ? s : ALPHA * s;
        }
    }
    __syncthreads();
    if (tid < 64) {                       // softmax over N=64 (wave 0)
        float s = sv[tid], m = s;
        #pragma unroll
        for (int o = 1; o < 64; o <<= 1) m = fmaxf(m, __shfl_xor(m, o));
        float e = __expf(s - m), t = e;
        #pragma unroll
        for (int o = 1; o < 64; o <<= 1) t += __shfl_xor(t, o);
        sv[tid] = e / t;
    }
    __syncthreads();
    // aggregation + per-b stats over the 64x256 tile
    float acc = 0.f, ss = 0.f, sq = 0.f;
    for (int n2 = 0; n2 < N_; ++n2) {
        const float v = tile[n2 * H1_ + tid];
        acc += sv[n2] * v;
        ss += v; sq += v * v;
    }
    out1[(size_t)b * H1_ + tid] = acc;
    const float rs = blk_reduce(ss, rbuf);
    const float rq = blk_reduce(sq, rbuf);
    if (tid == 0) {
        const float inv = 1.f / (float)(N_ * H1_);
        const float mean = rs * inv, var = rq * inv - mean * mean;
        const float a = (*g1p) * rsqrtf(var + BN_EPS);
        alpha1[b] = a; beta1[b] = (*be1p) - a * mean;
    }
}

// ---------------------------------------------------------------------------
// Layer-2 softmax + aggregation.  grid: 1024 x 256
// ---------------------------------------------------------------------------
__global__ __launch_bounds__(256) void k_agg2(
    const float* __restrict__ nbh2, const float* __restrict__ sself2,
    const float* __restrict__ a22, float* __restrict__ out2)
{
    __shared__ float tile[N_ * H2_];   // 32 KiB
    __shared__ float a22s[H2_];
    __shared__ float sv[N_];
    const int b = blockIdx.x, tid = threadIdx.x;
    const float* src = nbh2 + (size_t)b * N_ * H2_;
    for (int i = tid; i < N_ * H2_ / 4; i += 256)
        ((float4*)tile)[i] = ((const float4*)src)[i];
    if (tid < H2_) a22s[tid] = a22[tid];
    __syncthreads();
    {
        const int n = tid >> 2, q = tid & 3;
        float p = 0.f;
        #pragma unroll 4
        for (int i = 0; i < 32; ++i) {
            const int h = q * 32 + ((i + tid) & 31);
            p += tile[n * H2_ + h] * a22s[h];
        }
        p += __shfl_xor(p, 1); p += __shfl_xor(p, 2);
        if (q == 0) {
            float s = sself2[b] + p;
            sv[n] = s > 0.f ? s : ALPHA * s;
        }
    }
    __syncthreads();
    if (tid < 64) {
        float s = sv[tid], m = s;
        #pragma unroll
        for (int o = 1; o < 64; o <<= 1) m = fmaxf(m, __shfl_xor(m, o));
        float e = __expf(s - m), t = e;
        #pragma unroll
        for (int o = 1; o < 64; o <<= 1) t += __shfl_xor(t, o);
        sv[tid] = e / t;
    }
    __syncthreads();
    if (tid < H2_) {
        float acc = 0.f;
        for (int n2 = 0; n2 < N_; ++n2) acc += sv[n2] * tile[n2 * H2_ + tid];
        out2[(size_t)b * H2_ + tid] = acc;
    }
}

// ---------------------------------------------------------------------------
// Global BN stats, two-stage.  k_bnred: grid 64 x 256.  k_bnfin: 1 x 64
// ---------------------------------------------------------------------------
__global__ __launch_bounds__(256) void k_bnred(
    const float* __restrict__ src, const int n,
    float* __restrict__ psum, float* __restrict__ psq)
{
    __shared__ float rbuf[8];
    float s = 0.f, q = 0.f;
    for (int i = blockIdx.x * 256 + threadIdx.x; i < n; i += 64 * 256) {
        const float v = src[i]; s += v; q += v * v;
    }
    const float rs = blk_reduce(s, rbuf);
    const float rq = blk_reduce(q, rbuf);
    if (threadIdx.x == 0) { psum[blockIdx.x] = rs; psq[blockIdx.x] = rq; }
}

__global__ void k_bnfin(
    const float* __restrict__ psum, const float* __restrict__ psq, const float n,
    const float* __restrict__ gp, const float* __restrict__ bep,
    float* __restrict__ axbx)
{
    const int tid = threadIdx.x;
    float s = psum[tid], q = psq[tid];
    #pragma unroll
    for (int o = 32; o > 0; o >>= 1) { s += __shfl_xor(s, o); q += __shfl_xor(q, o); }
    if (tid == 0) {
        const float mean = s / n, var = q / n - mean * mean;
        const float a = (*gp) * rsqrtf(var + BN_EPS);
        axbx[0] = a; axbx[1] = (*bep) - a * mean;
    }
}

// ---------------------------------------------------------------------------
// sself2[b] = sum_k relu(ax1*out1[b,k]+bx1) * w2a[k] + c2.  grid: 1024 x 256
// ---------------------------------------------------------------------------
__global__ __launch_bounds__(256) void k_sself2(
    const float* __restrict__ out1, const float* __restrict__ axbx,
    const float* __restrict__ w2a, const float* __restrict__ cscal,
    float* __restrict__ sself2)
{
    __shared__ float rbuf[8];
    const int b = blockIdx.x, tid = threadIdx.x;
    const float ax = axbx[0], bx = axbx[1];
    const float v = out1[(size_t)b * H1_ + tid];
    const float x2 = fmaxf(fmaf(ax, v, bx), 0.f);
    float r = blk_reduce(x2 * w2a[tid], rbuf);
    if (tid == 0) sself2[b] = r + cscal[1];
}

// ---------------------------------------------------------------------------
// logits[b,c] = bl[c] + sum_h relu(ax2*out2[b,h]+bx2) * Wl[c,h].  grid: 1024x128
// ---------------------------------------------------------------------------
__global__ __launch_bounds__(128) void k_final(
    const float* __restrict__ out2, const float* __restrict__ axbx2,
    const float* __restrict__ Wl, const float* __restrict__ bl,
    float* __restrict__ logits)
{
    __shared__ float xr[H2_];
    __shared__ float Ws[NC_][H2_ + 1];   // +1 pad: conflict-free column reads
    const int b = blockIdx.x, tid = threadIdx.x;
    const float ax = axbx2[0], bx = axbx2[1];
    xr[tid] = fmaxf(fmaf(ax, out2[(size_t)b * H2_ + tid], bx), 0.f);
    for (int i = tid; i < NC_ * H2_ / 4; i += 128) {
        float4 v = ((const float4*)Wl)[i];
        const int r = i >> 5, c = (i & 31) * 4;
        Ws[r][c] = v.x; Ws[r][c + 1] = v.y; Ws[r][c + 2] = v.z; Ws[r][c + 3] = v.w;
    }
    __syncthreads();
    float acc = bl[tid];
    #pragma unroll 4
    for (int h = 0; h < H2_; ++h) acc += xr[h] * Ws[tid][h];
    logits[(size_t)b * NC_ + tid] = acc;
}

// ---------------------------------------------------------------------------
extern "C" void kernel_launch(void* const* d_in, const int* in_sizes, int n_in,
                              void* d_out, int out_size, void* d_ws, size_t ws_size,
                              hipStream_t stream)
{
    const float* x   = (const float*)d_in[0];
    const float* nb  = (const float*)d_in[1];
    const float* W1  = (const float*)d_in[2];
    const float* b1  = (const float*)d_in[3];
    const float* a11 = (const float*)d_in[4];
    const float* a12 = (const float*)d_in[5];
    const float* g1  = (const float*)d_in[6];
    const float* be1 = (const float*)d_in[7];
    const float* W2  = (const float*)d_in[8];
    const float* b2  = (const float*)d_in[9];
    const float* a21 = (const float*)d_in[10];
    const float* a22 = (const float*)d_in[11];
    const float* g2  = (const float*)d_in[12];
    const float* be2 = (const float*)d_in[13];
    const float* Wl  = (const float*)d_in[14];
    const float* bl  = (const float*)d_in[15];
    float* logits = (float*)d_out;

    // workspace carve-up (~104 MB total)
    size_t off = 0;
    auto alc = [&](size_t bytes) {
        void* p = (char*)d_ws + off;
        off = (off + bytes + 255) & ~(size_t)255;
        return p;
    };
    __bf16* W1b   = (__bf16*)alc((size_t)H1_ * F_ * 2);
    __bf16* W2b   = (__bf16*)alc((size_t)H2_ * H1_ * 2);
    float* w1a    = (float*)alc(F_ * 4);
    float* w2a    = (float*)alc(H1_ * 4);
    float* cscal  = (float*)alc(2 * 4);
    float* sself1 = (float*)alc(B_ * 4);
    float* sself2 = (float*)alc(B_ * 4);
    float* alpha1 = (float*)alc(B_ * 4);
    float* beta1  = (float*)alc(B_ * 4);
    float* psum   = (float*)alc(64 * 4);
    float* psq    = (float*)alc(64 * 4);
    float* axbx1  = (float*)alc(2 * 4);
    float* axbx2  = (float*)alc(2 * 4);
    float* out1   = (float*)alc((size_t)B_ * H1_ * 4);
    float* out2   = (float*)alc((size_t)B_ * H2_ * 4);
    float* nbh1   = (float*)alc((size_t)B_ * N_ * H1_ * 4);   // 64 MiB
    float* nbh2   = (float*)alc((size_t)B_ * N_ * H2_ * 4);   // 32 MiB

    k_prep<<<294, 256, 0, stream>>>(W1, W2, b1, a11, b2, a21, W1b, W2b, w1a, w2a, cscal);
    k_sself1<<<B_, 256, 0, stream>>>(x, w1a, cscal, sself1);
    k_gemm<256, 0><<<(B_ * N_) / 128, 256, 0, stream>>>(
        nb, F_, W1b, b1, nullptr, nullptr, 0, nbh1);
    k_agg1<<<B_, 256, 0, stream>>>(nbh1, sself1, a12, g1, be1, out1, alpha1, beta1);
    k_bnred<<<64, 256, 0, stream>>>(out1, B_ * H1_, psum, psq);
    k_bnfin<<<1, 64, 0, stream>>>(psum, psq, (float)(B_ * H1_), g1, be1, axbx1);
    k_sself2<<<B_, 256, 0, stream>>>(out1, axbx1, w2a, cscal, sself2);
    k_gemm<128, 1><<<(B_ * N_) / 128, 256, 0, stream>>>(
        nbh1, H1_, W2b, b2, alpha1, beta1, 6, nbh2);
    k_agg2<<<B_, 256, 0, stream>>>(nbh2, sself2, a22, out2);
    k_bnred<<<64, 256, 0, stream>>>(out2, B_ * H2_, psum, psq);
    k_bnfin<<<1, 64, 0, stream>>>(psum, psq, (float)(B_ * H2_), g2, be2, axbx2);
    k_final<<<B_, 128, 0, stream>>>(out2, axbx2, Wl, bl, logits);
}

// Round 2
// 501.468 us; speedup vs baseline: 1.0330x; 1.0330x over previous
//
#include <hip/hip_runtime.h>
#include <hip/hip_bf16.h>
#include <stdint.h>

#define B_    1024
#define N_    64
#define F_    1024
#define H1_   256
#define H2_   128
#define NC_   128
#define ALPHA 0.2f
#define BN_EPS 1e-5f

typedef __attribute__((ext_vector_type(4))) float  f32x4;
typedef __attribute__((ext_vector_type(8))) __bf16 bf16x8;
typedef __attribute__((ext_vector_type(4))) __bf16 bf16x4;

__device__ inline float sign_ref(float v) {
    // matches v / max(|v|, 1e-12): exact +-1 for |v| >= 1e-12
    float s = copysignf(1.0f, v);
    return (fabsf(v) >= 1e-12f) ? s : v * 1e12f;
}

__device__ __forceinline__ void gload_lds16(const void* g, void* l) {
    auto gp = reinterpret_cast<const __attribute__((address_space(1))) void*>(
        reinterpret_cast<uintptr_t>(g));
    auto lp = reinterpret_cast<__attribute__((address_space(3))) void*>(
        reinterpret_cast<uintptr_t>(l));
    __builtin_amdgcn_global_load_lds(gp, lp, 16, 0, 0);
}

__device__ inline float blk_reduce(float v, float* buf) {
    #pragma unroll
    for (int o = 32; o > 0; o >>= 1) v += __shfl_xor(v, o, 64);
    __syncthreads();
    const int wave = threadIdx.x >> 6, lane = threadIdx.x & 63;
    if (lane == 0) buf[wave] = v;
    __syncthreads();
    float r = 0.f;
    if (threadIdx.x == 0) {
        const int nw = blockDim.x >> 6;
        for (int i = 0; i < nw; ++i) r += buf[i];
    }
    return r;  // valid on thread 0 only
}

// ---------------------------------------------------------------------------
// Prep: W1,W2 -> bf16; w1a=W1^T a11; w1a12=W1^T a12; w2a=W2^T a21;
// w2a22=W2^T a22; c1=b1.a11, c2=b2.a21, c2p=b2.a22.   grid: 294 x 256
// ---------------------------------------------------------------------------
__global__ __launch_bounds__(256) void k_prep(
    const float* __restrict__ W1, const float* __restrict__ W2,
    const float* __restrict__ b1, const float* __restrict__ a11,
    const float* __restrict__ a12, const float* __restrict__ b2,
    const float* __restrict__ a21, const float* __restrict__ a22,
    __bf16* __restrict__ W1b, __bf16* __restrict__ W2b,
    float* __restrict__ w1a, float* __restrict__ w1a12,
    float* __restrict__ w2a, float* __restrict__ w2a22,
    float* __restrict__ cscal)
{
    __shared__ float rbuf[8];
    const int blk = blockIdx.x, tid = threadIdx.x;
    if (blk < 256) {                       // W1 -> bf16
        const int i0 = blk * 1024 + tid * 4;
        float4 v = *(const float4*)(W1 + i0);
        bf16x4 p = { (__bf16)v.x, (__bf16)v.y, (__bf16)v.z, (__bf16)v.w };
        *(bf16x4*)(W1b + i0) = p;
    } else if (blk < 288) {                // W2 -> bf16
        const int i0 = (blk - 256) * 1024 + tid * 4;
        float4 v = *(const float4*)(W2 + i0);
        bf16x4 p = { (__bf16)v.x, (__bf16)v.y, (__bf16)v.z, (__bf16)v.w };
        *(bf16x4*)(W2b + i0) = p;
    } else if (blk < 292) {                // W1^T {a11,a12}
        const int f = (blk - 288) * 256 + tid;
        float s1 = 0.f, s2 = 0.f;
        for (int h = 0; h < H1_; ++h) {
            const float w = W1[h * F_ + f];
            s1 += w * a11[h]; s2 += w * a12[h];
        }
        w1a[f] = s1; w1a12[f] = s2;
    } else if (blk == 292) {               // W2^T {a21,a22}
        float s1 = 0.f, s2 = 0.f;
        for (int h = 0; h < H2_; ++h) {
            const float w = W2[h * H1_ + tid];
            s1 += w * a21[h]; s2 += w * a22[h];
        }
        w2a[tid] = s1; w2a22[tid] = s2;
    } else {                               // scalars
        float v1 = b1[tid] * a11[tid];
        float v2 = (tid < H2_) ? b2[tid] * a21[tid] : 0.f;
        float v3 = (tid < H2_) ? b2[tid] * a22[tid] : 0.f;
        float r1 = blk_reduce(v1, rbuf);
        float r2 = blk_reduce(v2, rbuf);
        float r3 = blk_reduce(v3, rbuf);
        if (tid == 0) { cscal[0] = r1; cscal[1] = r2; cscal[2] = r3; }
    }
}

// ---------------------------------------------------------------------------
// sself1[b] = sum_f sign(x[b,f]) * w1a[f] + c1     grid: 1024 x 256
// ---------------------------------------------------------------------------
__global__ __launch_bounds__(256) void k_sself1(
    const float* __restrict__ x, const float* __restrict__ w1a,
    const float* __restrict__ cscal, float* __restrict__ sself1)
{
    __shared__ float rbuf[8];
    const int b = blockIdx.x, tid = threadIdx.x;
    const float* xb = x + (size_t)b * F_;
    float p = 0.f;
    for (int i = tid; i < F_; i += 256) p += sign_ref(xb[i]) * w1a[i];
    float r = blk_reduce(p, rbuf);
    if (tid == 0) sself1[b] = r + cscal[0];
}

// ---------------------------------------------------------------------------
// GEMM1: nbh1[BM x 256] = sign(A) @ W1b^T + b1, output bf16.
// BM=128, BK=64; B-tile via global_load_lds with XOR-swizzled chunks.
// grid: 512 x 256
// ---------------------------------------------------------------------------
__global__ __launch_bounds__(256, 1) void k_gemm1(
    const float* __restrict__ A, const __bf16* __restrict__ Bw,
    const float* __restrict__ bias, __bf16* __restrict__ C)
{
    constexpr int BM = 128, BN = 256, BK = 64, K = F_;
    constexpr int LDA = BK + 8;
    __shared__ __attribute__((aligned(16))) char smem[BM * LDA * 2 + BN * BK * 2];
    __bf16* As = (__bf16*)smem;                    // [BM][LDA], padded
    __bf16* Bs = (__bf16*)(smem + BM * LDA * 2);   // [BN*BK], swizzled 16B chunks
    __bf16* Cs = Bs;                               // reused in epilogue: [64][256]

    const int tid = threadIdx.x;
    const int wave = tid >> 6, lane = tid & 63;
    const int wm = wave & 1, wn = wave >> 1;
    const int rowin = lane & 15, kq = lane >> 4;
    const size_t m0 = (size_t)blockIdx.x * BM;

    f32x4 acc[4][8] = {};

    const int cqA = tid & 15, r0A = tid >> 4;
    const float* Abase = A + m0 * K + cqA * 4;

    for (int k0 = 0; k0 < K; k0 += BK) {
        // async global->LDS stage of B chunks (swizzled: slot (r,c8) holds
        // global chunk (r, c8 ^ (r&7)))
        #pragma unroll
        for (int it = 0; it < 8; ++it) {
            const int s = it * 256 + tid;
            const int r = s >> 3;
            const int c8 = (s & 7) ^ (r & 7);
            gload_lds16(Bw + (size_t)r * K + k0 + c8 * 8, Bs + s * 8);
        }
        // stage A with sign transform (fp32 -> +-1 bf16)
        #pragma unroll
        for (int rr = 0; rr < 8; ++rr) {
            const int r = r0A + rr * 16;
            float4 v = *(const float4*)(Abase + (size_t)r * K + k0);
            bf16x4 p = { (__bf16)sign_ref(v.x), (__bf16)sign_ref(v.y),
                         (__bf16)sign_ref(v.z), (__bf16)sign_ref(v.w) };
            *(bf16x4*)&As[r * LDA + cqA * 4] = p;
        }
        __syncthreads();
        #pragma unroll
        for (int ks = 0; ks < 2; ++ks) {
            bf16x8 af[4], bv[8];
            #pragma unroll
            for (int mi = 0; mi < 4; ++mi)
                af[mi] = *(const bf16x8*)&As[(wm * 64 + mi * 16 + rowin) * LDA + ks * 32 + kq * 8];
            #pragma unroll
            for (int ni = 0; ni < 8; ++ni) {
                const int r = wn * 128 + ni * 16 + rowin;
                const int c = (ks * 4 + kq) ^ (r & 7);
                bv[ni] = *(const bf16x8*)&Bs[(r * 8 + c) * 8];
            }
            #pragma unroll
            for (int mi = 0; mi < 4; ++mi)
                #pragma unroll
                for (int ni = 0; ni < 8; ++ni)
                    acc[mi][ni] = __builtin_amdgcn_mfma_f32_16x16x32_bf16(
                        af[mi], bv[ni], acc[mi][ni], 0, 0, 0);
        }
        __syncthreads();
    }
    // epilogue: +bias, cvt bf16, coalesced store via LDS (two 64-row halves)
    const int cr0 = (lane >> 4) * 4, cc = lane & 15;
    for (int half = 0; half < 2; ++half) {
        if (wm == half) {
            #pragma unroll
            for (int ni = 0; ni < 8; ++ni) {
                const int col = wn * 128 + ni * 16 + cc;
                const float bs = bias[col];
                #pragma unroll
                for (int mi = 0; mi < 4; ++mi)
                    #pragma unroll
                    for (int i = 0; i < 4; ++i)
                        Cs[(mi * 16 + cr0 + i) * 256 + col] =
                            (__bf16)(acc[mi][ni][i] + bs);
            }
        }
        __syncthreads();
        #pragma unroll
        for (int it = 0; it < 8; ++it) {
            const int s = it * 256 + tid;                  // 16B chunk id
            const size_t row = m0 + half * 64 + (s >> 5);
            *(bf16x8*)(C + row * 256 + (s & 31) * 8) = *(const bf16x8*)&Cs[s * 8];
        }
        __syncthreads();
    }
}

// ---------------------------------------------------------------------------
// Layer-1 softmax + aggregation + per-b BN stats (bf16 tile).  grid: 1024x256
// ---------------------------------------------------------------------------
__global__ __launch_bounds__(256) void k_agg1(
    const __bf16* __restrict__ nbh1, const float* __restrict__ sself1,
    const float* __restrict__ a12, const float* __restrict__ g1p,
    const float* __restrict__ be1p, float* __restrict__ out1,
    float* __restrict__ alpha1, float* __restrict__ beta1)
{
    __shared__ __attribute__((aligned(16))) __bf16 tile[N_ * H1_];  // 32 KB
    __shared__ float a12s[H1_];
    __shared__ float sv[N_];
    __shared__ float rbuf[8];
    const int b = blockIdx.x, tid = threadIdx.x;
    const __bf16* src = nbh1 + (size_t)b * N_ * H1_;
    #pragma unroll
    for (int it = 0; it < 8; ++it)
        ((bf16x8*)tile)[it * 256 + tid] = ((const bf16x8*)src)[it * 256 + tid];
    a12s[tid] = a12[tid];
    __syncthreads();
    {
        const int n = tid >> 2, q = tid & 3;
        float p = 0.f;
        for (int i = 0; i < 64; ++i) {
            const int h = q * 64 + ((i + tid) & 63);   // stagger banks
            p += (float)tile[n * H1_ + h] * a12s[h];
        }
        p += __shfl_xor(p, 1); p += __shfl_xor(p, 2);
        if (q == 0) { float s = sself1[b] + p; sv[n] = s > 0.f ? s : ALPHA * s; }
    }
    __syncthreads();
    if (tid < 64) {
        float s = sv[tid], m = s;
        #pragma unroll
        for (int o = 1; o < 64; o <<= 1) m = fmaxf(m, __shfl_xor(m, o));
        float e = __expf(s - m), t = e;
        #pragma unroll
        for (int o = 1; o < 64; o <<= 1) t += __shfl_xor(t, o);
        sv[tid] = e / t;
    }
    __syncthreads();
    float acc = 0.f, ss = 0.f, sq = 0.f;
    for (int n2 = 0; n2 < N_; ++n2) {
        const float v = (float)tile[n2 * H1_ + tid];
        acc += sv[n2] * v; ss += v; sq += v * v;
    }
    out1[(size_t)b * H1_ + tid] = acc;
    const float rs = blk_reduce(ss, rbuf);
    const float rq = blk_reduce(sq, rbuf);
    if (tid == 0) {
        const float inv = 1.f / (float)(N_ * H1_);
        const float mean = rs * inv, var = rq * inv - mean * mean;
        const float a = (*g1p) * rsqrtf(var + BN_EPS);
        alpha1[b] = a; beta1[b] = (*be1p) - a * mean;
    }
}

// ---------------------------------------------------------------------------
// Partial sums for global BN.  grid: 64 x 256
// ---------------------------------------------------------------------------
__global__ __launch_bounds__(256) void k_bnred(
    const float* __restrict__ src, const int n,
    float* __restrict__ psum, float* __restrict__ psq)
{
    __shared__ float rbuf[8];
    float s = 0.f, q = 0.f;
    for (int i = blockIdx.x * 256 + threadIdx.x; i < n; i += 64 * 256) {
        const float v = src[i]; s += v; q += v * v;
    }
    const float rs = blk_reduce(s, rbuf);
    const float rq = blk_reduce(q, rbuf);
    if (threadIdx.x == 0) { psum[blockIdx.x] = rs; psq[blockIdx.x] = rq; }
}

// ---------------------------------------------------------------------------
// sself2[b] = sum_k relu(ax1*out1[b,k]+bx1) * w2a[k] + c2 (fin1 inlined).
// grid: 1024 x 256
// ---------------------------------------------------------------------------
__global__ __launch_bounds__(256) void k_sself2(
    const float* __restrict__ out1, const float* __restrict__ psum,
    const float* __restrict__ psq, const float* __restrict__ gp,
    const float* __restrict__ bep, const float* __restrict__ w2a,
    const float* __restrict__ cscal, float* __restrict__ sself2)
{
    __shared__ float rbuf[8];
    __shared__ float axbx[2];
    const int b = blockIdx.x, tid = threadIdx.x;
    if (tid < 64) {
        float s = psum[tid], q = psq[tid];
        #pragma unroll
        for (int o = 32; o > 0; o >>= 1) { s += __shfl_xor(s, o); q += __shfl_xor(q, o); }
        if (tid == 0) {
            const float n = (float)(B_ * H1_);
            const float mean = s / n, var = q / n - mean * mean;
            const float a = (*gp) * rsqrtf(var + BN_EPS);
            axbx[0] = a; axbx[1] = (*bep) - a * mean;
        }
    }
    __syncthreads();
    const float ax = axbx[0], bx = axbx[1];
    const float v = out1[(size_t)b * H1_ + tid];
    const float x2 = fmaxf(fmaf(ax, v, bx), 0.f);
    float r = blk_reduce(x2 * w2a[tid], rbuf);
    if (tid == 0) sself2[b] = r + cscal[1];
}

// ---------------------------------------------------------------------------
// Layer-2 fully fused per b: act1 -> scores -> softmax -> weighted combo ->
// out2 = combo @ W2^T + b2.   grid: 1024 x 256
// ---------------------------------------------------------------------------
__global__ __launch_bounds__(256) void k_agg2(
    const __bf16* __restrict__ nbh1, const float* __restrict__ alpha1,
    const float* __restrict__ beta1, const float* __restrict__ sself2,
    const float* __restrict__ w2a22, const float* __restrict__ cscal,
    const __bf16* __restrict__ W2b, const float* __restrict__ b2,
    float* __restrict__ out2)
{
    __shared__ __attribute__((aligned(16))) __bf16 tile[N_ * H1_];  // 32 KB
    __shared__ float wv[H1_];
    __shared__ float sv[N_];
    __shared__ float g2s[H1_ + 8];    // swizzled: k stored at k + (k>>5)
    __shared__ float hpart[H2_];
    const int b = blockIdx.x, tid = threadIdx.x;
    const __bf16* src = nbh1 + (size_t)b * N_ * H1_;
    #pragma unroll
    for (int it = 0; it < 8; ++it)
        ((bf16x8*)tile)[it * 256 + tid] = ((const bf16x8*)src)[it * 256 + tid];
    wv[tid] = w2a22[tid];
    const float al = alpha1[b], be = beta1[b];
    __syncthreads();
    {   // scores: s2[n] = sself2 + act1(row_n) . w2a22 + c2p
        const int n = tid >> 2, q = tid & 3;
        float p = 0.f;
        for (int i = 0; i < 64; ++i) {
            const int h = q * 64 + ((i + tid) & 63);
            const float v = (float)tile[n * H1_ + h];
            p += fmaxf(fmaf(al, v, be), 0.f) * wv[h];
        }
        p += __shfl_xor(p, 1); p += __shfl_xor(p, 2);
        if (q == 0) {
            float s = sself2[b] + p + cscal[2];
            sv[n] = s > 0.f ? s : ALPHA * s;
        }
    }
    __syncthreads();
    if (tid < 64) {
        float s = sv[tid], m = s;
        #pragma unroll
        for (int o = 1; o < 64; o <<= 1) m = fmaxf(m, __shfl_xor(m, o));
        float e = __expf(s - m), t = e;
        #pragma unroll
        for (int o = 1; o < 64; o <<= 1) t += __shfl_xor(t, o);
        sv[tid] = e / t;
    }
    __syncthreads();
    {   // weighted combo over neighbors (k = tid)
        float g = 0.f;
        for (int n2 = 0; n2 < N_; ++n2) {
            const float v = (float)tile[n2 * H1_ + tid];
            g += sv[n2] * fmaxf(fmaf(al, v, be), 0.f);
        }
        g2s[tid + (tid >> 5)] = g;
    }
    __syncthreads();
    // out2 = g2 @ W2^T + b2 : 16 sweeps, 32 lanes per output h
    #pragma unroll 4
    for (int j = 0; j < 16; ++j) {
        const int idx = j * 256 + tid;       // bf16x8 chunk of W2b
        const int h = idx >> 5, k8 = idx & 31;
        const bf16x8 w = ((const bf16x8*)W2b)[idx];
        float p = 0.f;
        #pragma unroll
        for (int i = 0; i < 8; ++i) {
            const int k = k8 * 8 + i;
            p += (float)w[i] * g2s[k + (k >> 5)];
        }
        p += __shfl_xor(p, 1); p += __shfl_xor(p, 2); p += __shfl_xor(p, 4);
        p += __shfl_xor(p, 8); p += __shfl_xor(p, 16);
        if ((tid & 31) == 0) hpart[h] = p;
    }
    __syncthreads();
    if (tid < H2_) out2[(size_t)b * H2_ + tid] = hpart[tid] + b2[tid];
}

// ---------------------------------------------------------------------------
// Final: BN2 (fin inlined) + ReLU + Linear.  grid: 1024 x 128
// ---------------------------------------------------------------------------
__global__ __launch_bounds__(128) void k_final(
    const float* __restrict__ out2, const float* __restrict__ psum,
    const float* __restrict__ psq, const float* __restrict__ gp,
    const float* __restrict__ bep, const float* __restrict__ Wl,
    const float* __restrict__ bl, float* __restrict__ logits)
{
    __shared__ float xr[H2_];
    __shared__ float Ws[NC_][H2_ + 1];
    __shared__ float axbx[2];
    const int b = blockIdx.x, tid = threadIdx.x;
    if (tid < 64) {
        float s = psum[tid], q = psq[tid];
        #pragma unroll
        for (int o = 32; o > 0; o >>= 1) { s += __shfl_xor(s, o); q += __shfl_xor(q, o); }
        if (tid == 0) {
            const float n = (float)(B_ * H2_);
            const float mean = s / n, var = q / n - mean * mean;
            const float a = (*gp) * rsqrtf(var + BN_EPS);
            axbx[0] = a; axbx[1] = (*bep) - a * mean;
        }
    }
    for (int i = tid; i < NC_ * H2_ / 4; i += 128) {
        float4 v = ((const float4*)Wl)[i];
        const int r = i >> 5, c = (i & 31) * 4;
        Ws[r][c] = v.x; Ws[r][c + 1] = v.y; Ws[r][c + 2] = v.z; Ws[r][c + 3] = v.w;
    }
    __syncthreads();
    xr[tid] = fmaxf(fmaf(axbx[0], out2[(size_t)b * H2_ + tid], axbx[1]), 0.f);
    __syncthreads();
    float acc = bl[tid];
    #pragma unroll 4
    for (int h = 0; h < H2_; ++h) acc += xr[h] * Ws[tid][h];
    logits[(size_t)b * NC_ + tid] = acc;
}

// ---------------------------------------------------------------------------
extern "C" void kernel_launch(void* const* d_in, const int* in_sizes, int n_in,
                              void* d_out, int out_size, void* d_ws, size_t ws_size,
                              hipStream_t stream)
{
    const float* x   = (const float*)d_in[0];
    const float* nb  = (const float*)d_in[1];
    const float* W1  = (const float*)d_in[2];
    const float* b1  = (const float*)d_in[3];
    const float* a11 = (const float*)d_in[4];
    const float* a12 = (const float*)d_in[5];
    const float* g1  = (const float*)d_in[6];
    const float* be1 = (const float*)d_in[7];
    const float* W2  = (const float*)d_in[8];
    const float* b2  = (const float*)d_in[9];
    const float* a21 = (const float*)d_in[10];
    const float* a22 = (const float*)d_in[11];
    const float* g2  = (const float*)d_in[12];
    const float* be2 = (const float*)d_in[13];
    const float* Wl  = (const float*)d_in[14];
    const float* bl  = (const float*)d_in[15];
    float* logits = (float*)d_out;

    size_t off = 0;
    auto alc = [&](size_t bytes) {
        void* p = (char*)d_ws + off;
        off = (off + bytes + 255) & ~(size_t)255;
        return p;
    };
    __bf16* W1b   = (__bf16*)alc((size_t)H1_ * F_ * 2);
    __bf16* W2b   = (__bf16*)alc((size_t)H2_ * H1_ * 2);
    float* w1a    = (float*)alc(F_ * 4);
    float* w1a12  = (float*)alc(F_ * 4);
    float* w2a    = (float*)alc(H1_ * 4);
    float* w2a22  = (float*)alc(H1_ * 4);
    float* cscal  = (float*)alc(3 * 4);
    float* sself1 = (float*)alc(B_ * 4);
    float* sself2 = (float*)alc(B_ * 4);
    float* alpha1 = (float*)alc(B_ * 4);
    float* beta1  = (float*)alc(B_ * 4);
    float* psum1  = (float*)alc(64 * 4);
    float* psq1   = (float*)alc(64 * 4);
    float* psum2  = (float*)alc(64 * 4);
    float* psq2   = (float*)alc(64 * 4);
    float* out1   = (float*)alc((size_t)B_ * H1_ * 4);
    float* out2   = (float*)alc((size_t)B_ * H2_ * 4);
    __bf16* nbh1  = (__bf16*)alc((size_t)B_ * N_ * H1_ * 2);   // 32 MiB

    k_prep<<<294, 256, 0, stream>>>(W1, W2, b1, a11, a12, b2, a21, a22,
                                    W1b, W2b, w1a, w1a12, w2a, w2a22, cscal);
    k_sself1<<<B_, 256, 0, stream>>>(x, w1a, cscal, sself1);
    k_gemm1<<<(B_ * N_) / 128, 256, 0, stream>>>(nb, W1b, b1, nbh1);
    k_agg1<<<B_, 256, 0, stream>>>(nbh1, sself1, a12, g1, be1, out1, alpha1, beta1);
    k_bnred<<<64, 256, 0, stream>>>(out1, B_ * H1_, psum1, psq1);
    k_sself2<<<B_, 256, 0, stream>>>(out1, psum1, psq1, g1, be1, w2a, cscal, sself2);
    k_agg2<<<B_, 256, 0, stream>>>(nbh1, alpha1, beta1, sself2, w2a22, cscal,
                                   W2b, b2, out2);
    k_bnred<<<64, 256, 0, stream>>>(out2, B_ * H2_, psum2, psq2);
    k_final<<<B_, 128, 0, stream>>>(out2, psum2, psq2, g2, be2, Wl, bl, logits);
}